// Round 14
// baseline (176.423 us; speedup 1.0000x reference)
//
#include <hip/hip_runtime.h>
#include <math.h>

#define NQ    12
#define DIM   4096        // 2^NQ
#define K_EXT 8192        // [hi | lo] extended row
#define KSL   1024        // K per slice (8 slices)
#define NSAMP 2048
#define NLAY  3
#define NT2   16          // 2048/128 tiles per dimension
#define NTRI2 136         // NT2*(NT2+1)/2 triangular tiles
#define NSLICE 8
#define BK    64
#define LDK   72          // LDS row stride (ushort); 144 B, 16B-aligned rows

typedef __attribute__((ext_vector_type(8)))  short bf16x8;   // 8 bf16 = 4 VGPRs
typedef __attribute__((ext_vector_type(16))) float floatx16; // MFMA 32x32 acc

__device__ __forceinline__ unsigned short f32_to_bf16(float x) {
    unsigned u = __builtin_bit_cast(unsigned, x);
    u += 0x7FFFu + ((u >> 16) & 1u);            // round-to-nearest-even
    return (unsigned short)(u >> 16);
}
__device__ __forceinline__ float bf16_to_f32(unsigned short h) {
    unsigned u = (unsigned)h << 16;
    return __builtin_bit_cast(float, u);
}

__device__ __forceinline__ void tri_decode(int bid, int& bi, int& bj) {
    int i = (int)((33.0 - sqrt(33.0*33.0 - 8.0*(double)bid)) * 0.5);
    int start = i*(33-i)/2;
    while (bid < start)               { --i; start = i*(33-i)/2; }
    while (bid >= start + (NT2 - i))  { start += NT2 - i; ++i; }
    bi = i; bj = i + (bid - start);
}

// ---------------------------------------------------------------------------
// Kernel 1: one sample per TWO waves (v[32]/lane) — UNCHANGED from R13.
// With gram_partial now at ~35-40us dispatches, this kernel finally surfaces
// in the top-5 profile for diagnosis next round.
// Bit map: i = r*128 + w*64 + lane.  CZ parity re-derived for this map.
// Emits psi = hi + lo as one extended bf16 row [hi(4096) | lo(4096)].
// (k-index permutation is sample-invariant -> Gram invariant.)
// ---------------------------------------------------------------------------
__global__ __launch_bounds__(256) void sim_kernel(const float* __restrict__ data,
                                                  const float* __restrict__ params,
                                                  unsigned short* __restrict__ pe)
{
    __shared__ float CS[2*36], SN[2*36];
    __shared__ float ex[2][128*33];     // +1 pad -> 2-way banks (free)
    const int tid  = threadIdx.x;
    const int wave = tid >> 6, lane = tid & 63;
    const int sidx = wave >> 1;         // sample within block
    const int w    = wave & 1;          // qubit-6 bit
    const int smp  = blockIdx.x * 2 + sidx;

    if (w == 0 && lane < NLAY*NQ) {
        const int q = lane % NQ;
        const float th = 0.5f * (params[lane] + data[smp*NQ + q]);
        CS[sidx*36 + lane] = cosf(th);
        SN[sidx*36 + lane] = sinf(th);
    }
    __syncthreads();

    float v[32];
    #pragma unroll
    for (int r = 0; r < 32; ++r) v[r] = 0.f;
    if (w == 0 && lane == 0) v[0] = 1.f;

    const int P5 = __popc(lane & (lane >> 1) & 0x1F) & 1;
    const int l0 = lane & 1, l5 = (lane >> 5) & 1;
    const int plw = P5 ^ (w & l5);
    const float fA = plw        ? -1.f : 1.f;   // r4=0
    const float fB = (plw ^ l0) ? -1.f : 1.f;   // r4=1
    const float fw = w ? -1.f : 1.f;            // applied when r0=1

    float*       exw = &ex[sidx][(w*64       + lane)*33];
    const float* exp_ = &ex[sidx][((1-w)*64  + lane)*33];

    #pragma unroll 1
    for (int l = 0; l < NLAY; ++l) {
        const float* cs = &CS[sidx*36 + l*NQ];
        const float* sn = &SN[sidx*36 + l*NQ];
        #pragma unroll 1
        for (int q = 0; q < 6; ++q) {
            const float c = cs[q], s = sn[q];
            const float t = ((lane >> q) & 1) ? s : -s;
            const int   m = 1 << q;
            #pragma unroll
            for (int r = 0; r < 32; ++r) {
                const float p = __shfl_xor(v[r], m, 64);
                v[r] = c * v[r] + t * p;
            }
        }
        {
            const float c = cs[6], s = sn[6];
            const float t = w ? s : -s;
            __syncthreads();
            #pragma unroll
            for (int r = 0; r < 32; ++r) exw[r] = v[r];
            __syncthreads();
            #pragma unroll
            for (int r = 0; r < 32; ++r) v[r] = c * v[r] + t * exp_[r];
        }
        #pragma unroll
        for (int b = 0; b < 5; ++b) {
            const float c = cs[7 + b], s = sn[7 + b];
            const int M = 1 << b;
            #pragma unroll
            for (int r = 0; r < 32; ++r) {
                if (!(r & M)) {
                    const float a0 = v[r], a1 = v[r | M];
                    v[r]     = c * a0 - s * a1;
                    v[r | M] = s * a0 + c * a1;
                }
            }
        }
        #pragma unroll
        for (int r = 0; r < 32; ++r) {
            const int P4 = __popc(r & (r >> 1) & 0xF) & 1;
            const int r0 = r & 1, r4 = (r >> 4) & 1;
            float f = r4 ? fB : fA;
            if (P4) f = -f;
            if (r0) f *= fw;
            v[r] *= f;
        }
    }

    unsigned short* outh = pe + (size_t)smp * K_EXT + w*64 + lane;
    unsigned short* outl = outh + DIM;
    #pragma unroll
    for (int r = 0; r < 32; ++r) {
        const float x = v[r];
        const unsigned short hb = f32_to_bf16(x);
        outh[r*128] = hb;
        outl[r*128] = f32_to_bf16(x - bf16_to_f32(hb));
    }
}

// ---------------------------------------------------------------------------
// Kernel 2a: partial Gram.  1088 blocks = 136 tiles x 8 K-slices.
// K-slicing is traffic-invariant (each tile reads its A/B once in total) but
// doubles co-residency to ~4.25 blocks/CU (LDS 36.9KB and 128 regs/wave both
// permit 4/CU) — R13's 544-block grid was the occupancy limiter.
// All registers NAMED (indexed register arrays spill on this compiler).
// ---------------------------------------------------------------------------
__global__ __launch_bounds__(256, 2) void gram_partial(const unsigned short* __restrict__ pe,
                                                       float* __restrict__ Gp)
{
    __shared__ __align__(16) unsigned short As[128*LDK];   // 18.4 KiB
    __shared__ __align__(16) unsigned short Bs[128*LDK];   // 18.4 KiB

    const int tid   = threadIdx.x;
    const int tile  = blockIdx.x % NTRI2;
    const int slice = blockIdx.x / NTRI2;
    int bi, bj; tri_decode(tile, bi, bj);
    const int k0 = slice * KSL;

    const int wave = tid >> 6, lane = tid & 63;
    const int qr = (wave >> 1) * 64;   // quadrant row offset
    const int qc = (wave &  1) * 64;   // quadrant col offset
    const int mrow = lane & 31;
    const int kgrp = (lane >> 5) * 8;  // A/B layout: lane holds M[lane&31][(lane>>5)*8+j]

    floatx16 c00, c01, c10, c11;
    #pragma unroll
    for (int i = 0; i < 16; ++i) { c00[i]=0.f; c01[i]=0.f; c10[i]=0.f; c11[i]=0.f; }

    const int r = tid >> 1;
    const int h = (tid & 1) * 32;      // ushort offset (64 B)
    const unsigned short* gA = pe + ((size_t)bi*128 + r) * K_EXT + k0 + h;
    const unsigned short* gB = pe + ((size_t)bj*128 + r) * K_EXT + k0 + h;
    unsigned short* sA = &As[r*LDK + h];
    unsigned short* sB = &Bs[r*LDK + h];

    uint4 pa0 = *(const uint4*)(gA +  0), pa1 = *(const uint4*)(gA +  8);
    uint4 pa2 = *(const uint4*)(gA + 16), pa3 = *(const uint4*)(gA + 24);
    uint4 pb0 = *(const uint4*)(gB +  0), pb1 = *(const uint4*)(gB +  8);
    uint4 pb2 = *(const uint4*)(gB + 16), pb3 = *(const uint4*)(gB + 24);

    for (int kk = 0; kk < KSL; kk += BK) {
        __syncthreads();                       // prev readers done
        *(uint4*)(sA +  0) = pa0; *(uint4*)(sA +  8) = pa1;
        *(uint4*)(sA + 16) = pa2; *(uint4*)(sA + 24) = pa3;
        *(uint4*)(sB +  0) = pb0; *(uint4*)(sB +  8) = pb1;
        *(uint4*)(sB + 16) = pb2; *(uint4*)(sB + 24) = pb3;
        __syncthreads();
        if (kk + BK < KSL) {                   // prefetch next stage
            pa0 = *(const uint4*)(gA + kk + BK +  0); pa1 = *(const uint4*)(gA + kk + BK +  8);
            pa2 = *(const uint4*)(gA + kk + BK + 16); pa3 = *(const uint4*)(gA + kk + BK + 24);
            pb0 = *(const uint4*)(gB + kk + BK +  0); pb1 = *(const uint4*)(gB + kk + BK +  8);
            pb2 = *(const uint4*)(gB + kk + BK + 16); pb3 = *(const uint4*)(gB + kk + BK + 24);
        }
        #pragma unroll
        for (int ks = 0; ks < 4; ++ks) {
            const int ro = ks*16 + kgrp;
            const bf16x8 a0 = *(const bf16x8*)&As[(qr +      mrow)*LDK + ro];
            const bf16x8 a1 = *(const bf16x8*)&As[(qr + 32 + mrow)*LDK + ro];
            const bf16x8 b0 = *(const bf16x8*)&Bs[(qc +      mrow)*LDK + ro];
            const bf16x8 b1 = *(const bf16x8*)&Bs[(qc + 32 + mrow)*LDK + ro];
            c00 = __builtin_amdgcn_mfma_f32_32x32x16_bf16(a0, b0, c00, 0, 0, 0);
            c01 = __builtin_amdgcn_mfma_f32_32x32x16_bf16(a0, b1, c01, 0, 0, 0);
            c10 = __builtin_amdgcn_mfma_f32_32x32x16_bf16(a1, b0, c10, 0, 0, 0);
            c11 = __builtin_amdgcn_mfma_f32_32x32x16_bf16(a1, b1, c11, 0, 0, 0);
        }
    }

    // Write partial G quadrants.  C/D layout (m74/m101).
    float* Gt = Gp + ((size_t)slice * NTRI2 + tile) * 16384;
    const int crow = (lane >> 5) * 4;
    const int ccol = lane & 31;
    #pragma unroll
    for (int rr = 0; rr < 16; ++rr) {
        const int rl = (rr & 3) + 8*(rr >> 2) + crow;    // 0..31
        const int r0 = qr + rl,  r1 = qr + 32 + rl;
        const int cA = qc + ccol, cB = qc + 32 + ccol;
        Gt[r0*128 + cA] = c00[rr];
        Gt[r0*128 + cB] = c01[rr];
        Gt[r1*128 + cA] = c10[rr];
        Gt[r1*128 + cB] = c11[rr];
    }
}

// ---------------------------------------------------------------------------
// Kernel 2b: sum the 8 K-slice partials, square, weight, reduce.
// 544 blocks, each a quarter-tile (4096 elements), 8 strided reads/elem.
// ---------------------------------------------------------------------------
__global__ __launch_bounds__(256) void gram_reduce(const float* __restrict__ Gp,
                                                   const int* __restrict__ labels,
                                                   double* __restrict__ part1,
                                                   double* __restrict__ part2)
{
    __shared__ float la[128], lb[128];
    __shared__ double red[256];
    const int tid  = threadIdx.x;
    const int tile = blockIdx.x >> 2;
    const int quar = blockIdx.x & 3;
    int bi, bj; tri_decode(tile, bi, bj);

    if (tid < 128) la[tid]       = 2.0f*(float)labels[bi*128 + tid]       - 1.0f;
    else           lb[tid - 128] = 2.0f*(float)labels[bj*128 + tid - 128] - 1.0f;
    __syncthreads();

    const size_t stride = (size_t)NTRI2 * 16384;
    const float* g0 = Gp + (size_t)tile * 16384 + quar * 4096;

    double s1 = 0.0, s2 = 0.0;
    #pragma unroll 2
    for (int u = 0; u < 16; ++u) {
        const int e  = u*256 + tid;          // 0..4095 within quarter
        const int ge = quar*4096 + e;
        float g = 0.f;
        #pragma unroll
        for (int s = 0; s < NSLICE; ++s) g += g0[e + (size_t)s*stride];
        const int row = ge >> 7, col = ge & 127;
        const float w = (bi < bj) ? 2.0f : ((row < col) ? 2.0f : ((row == col) ? 1.0f : 0.0f));
        const float g2 = g * g;
        s1 += (double)(w * la[row] * lb[col] * g2);
        const double d = (double)g2;
        s2 += (double)w * d * d;
    }

    red[tid] = s1; __syncthreads();
    for (int off = 128; off; off >>= 1) { if (tid < off) red[tid] += red[tid+off]; __syncthreads(); }
    if (tid == 0) part1[blockIdx.x] = red[0];
    __syncthreads();
    red[tid] = s2; __syncthreads();
    for (int off = 128; off; off >>= 1) { if (tid < off) red[tid] += red[tid+off]; __syncthreads(); }
    if (tid == 0) part2[blockIdx.x] = red[0];
}

// ---------------------------------------------------------------------------
// Kernel 3: reduce 544 partial slots -> scalar f32.
// square_sum_l = N^2 exactly, so out = s1 / (N * sqrt(s2)).
// ---------------------------------------------------------------------------
__global__ __launch_bounds__(256) void finalize_kernel(const double* __restrict__ part1,
                                                       const double* __restrict__ part2,
                                                       float* __restrict__ out)
{
    __shared__ double r1[256], r2[256];
    const int tid = threadIdx.x;
    double a = 0.0, b = 0.0;
    #pragma unroll
    for (int u = 0; u < 3; ++u) {
        const int s = tid + u*256;
        if (s < NTRI2*4) { a += part1[s]; b += part2[s]; }
    }
    r1[tid] = a; r2[tid] = b; __syncthreads();
    for (int off = 128; off; off >>= 1) {
        if (tid < off) { r1[tid] += r1[tid+off]; r2[tid] += r2[tid+off]; }
        __syncthreads();
    }
    if (tid == 0) out[0] = (float)(r1[0] / (sqrt(r2[0]) * (double)NSAMP));
}

// ---------------------------------------------------------------------------
extern "C" void kernel_launch(void* const* d_in, const int* in_sizes, int n_in,
                              void* d_out, int out_size, void* d_ws, size_t ws_size,
                              hipStream_t stream)
{
    const float* data   = (const float*)d_in[0]; // (2048,12) f32
    const int*   labels = (const int*)d_in[1];   // (2048,)   i32
    const float* params = (const float*)d_in[2]; // (3,12)    f32

    double* part1 = (double*)d_ws;                                    // 544 (pad 768) doubles
    double* part2 = part1 + 768;                                      // 544 doubles
    unsigned short* psi_ext = (unsigned short*)((char*)d_ws + 16384); // 32 MiB
    float* Gp = (float*)((char*)d_ws + 16384 + (size_t)NSAMP*K_EXT*2);// 8x136x16384 f32 = 71.3 MiB

    sim_kernel<<<NSAMP/2, 256, 0, stream>>>(data, params, psi_ext);
    gram_partial<<<NTRI2*NSLICE, 256, 0, stream>>>(psi_ext, Gp);
    gram_reduce<<<NTRI2*4, 256, 0, stream>>>(Gp, labels, part1, part2);
    finalize_kernel<<<1, 256, 0, stream>>>(part1, part2, (float*)d_out);
}

// Round 15
// 155.176 us; speedup vs baseline: 1.1369x; 1.1369x over previous
//
#include <hip/hip_runtime.h>
#include <math.h>

#define NQ    12
#define DIM   4096        // 2^NQ
#define K_EXT 8192        // [hi | lo] extended row
#define KSL   1024        // K per slice (8 slices)
#define NSAMP 2048
#define NLAY  3
#define NT2   16          // 2048/128 tiles per dimension
#define NTRI2 136         // NT2*(NT2+1)/2 triangular tiles
#define NSLICE 8
#define BK    64
#define LDK   72          // LDS row stride (ushort); 144 B, 16B-aligned rows

typedef __attribute__((ext_vector_type(8)))  short bf16x8;   // 8 bf16 = 4 VGPRs
typedef __attribute__((ext_vector_type(16))) float floatx16; // MFMA 32x32 acc

__device__ __forceinline__ unsigned short f32_to_bf16(float x) {
    unsigned u = __builtin_bit_cast(unsigned, x);
    u += 0x7FFFu + ((u >> 16) & 1u);            // round-to-nearest-even
    return (unsigned short)(u >> 16);
}
__device__ __forceinline__ float bf16_to_f32(unsigned short h) {
    unsigned u = (unsigned)h << 16;
    return __builtin_bit_cast(float, u);
}

__device__ __forceinline__ void tri_decode(int bid, int& bi, int& bj) {
    int i = (int)((33.0 - sqrt(33.0*33.0 - 8.0*(double)bid)) * 0.5);
    int start = i*(33-i)/2;
    while (bid < start)               { --i; start = i*(33-i)/2; }
    while (bid >= start + (NT2 - i))  { start += NT2 - i; ++i; }
    bi = i; bj = i + (bid - start);
}

// ---------------------------------------------------------------------------
// Kernel 1: one sample per TWO waves (v[32]/lane).
// Qubit-0/1 butterflies use DPP quad_perm (VALU pipe) instead of shfl
// (ds_bpermute, LDS pipe) — sim is bpermute-throughput-bound; this removes
// 1/3 of the LDS-pipe ops.  xor1 = quad_perm[1,0,3,2] = 0xB1,
// xor2 = quad_perm[2,3,0,1] = 0x4E.
// Bit map: i = r*128 + w*64 + lane.  CZ parity re-derived for this map.
// Emits psi = hi + lo as one extended bf16 row [hi(4096) | lo(4096)].
// ---------------------------------------------------------------------------
__global__ __launch_bounds__(256) void sim_kernel(const float* __restrict__ data,
                                                  const float* __restrict__ params,
                                                  unsigned short* __restrict__ pe)
{
    __shared__ float CS[2*36], SN[2*36];
    __shared__ float ex[2][128*33];     // +1 pad -> 2-way banks (free)
    const int tid  = threadIdx.x;
    const int wave = tid >> 6, lane = tid & 63;
    const int sidx = wave >> 1;         // sample within block
    const int w    = wave & 1;          // qubit-6 bit
    const int smp  = blockIdx.x * 2 + sidx;

    if (w == 0 && lane < NLAY*NQ) {
        const int q = lane % NQ;
        const float th = 0.5f * (params[lane] + data[smp*NQ + q]);
        CS[sidx*36 + lane] = cosf(th);
        SN[sidx*36 + lane] = sinf(th);
    }
    __syncthreads();

    float v[32];
    #pragma unroll
    for (int r = 0; r < 32; ++r) v[r] = 0.f;
    if (w == 0 && lane == 0) v[0] = 1.f;

    const int P5 = __popc(lane & (lane >> 1) & 0x1F) & 1;
    const int l0 = lane & 1, l5 = (lane >> 5) & 1;
    const int plw = P5 ^ (w & l5);
    const float fA = plw        ? -1.f : 1.f;   // r4=0
    const float fB = (plw ^ l0) ? -1.f : 1.f;   // r4=1
    const float fw = w ? -1.f : 1.f;            // applied when r0=1

    float*       exw = &ex[sidx][(w*64       + lane)*33];
    const float* exp_ = &ex[sidx][((1-w)*64  + lane)*33];

    #pragma unroll 1
    for (int l = 0; l < NLAY; ++l) {
        const float* cs = &CS[sidx*36 + l*NQ];
        const float* sn = &SN[sidx*36 + l*NQ];
        // qubits 0,1: DPP quad_perm butterflies (VALU pipe)
        {
            const float c0 = cs[0], s0 = sn[0];
            const float t0 = (lane & 1) ? s0 : -s0;
            #pragma unroll
            for (int r = 0; r < 32; ++r) {
                const int iv = __builtin_bit_cast(int, v[r]);
                const int pv = __builtin_amdgcn_update_dpp(0, iv, 0xB1, 0xF, 0xF, true);
                v[r] = c0 * v[r] + t0 * __builtin_bit_cast(float, pv);
            }
            const float c1 = cs[1], s1 = sn[1];
            const float t1 = (lane & 2) ? s1 : -s1;
            #pragma unroll
            for (int r = 0; r < 32; ++r) {
                const int iv = __builtin_bit_cast(int, v[r]);
                const int pv = __builtin_amdgcn_update_dpp(0, iv, 0x4E, 0xF, 0xF, true);
                v[r] = c1 * v[r] + t1 * __builtin_bit_cast(float, pv);
            }
        }
        // qubits 2-5: lane shfl butterflies (ds_bpermute)
        #pragma unroll 1
        for (int q = 2; q < 6; ++q) {
            const float c = cs[q], s = sn[q];
            const float t = ((lane >> q) & 1) ? s : -s;
            const int   m = 1 << q;
            #pragma unroll
            for (int r = 0; r < 32; ++r) {
                const float p = __shfl_xor(v[r], m, 64);
                v[r] = c * v[r] + t * p;
            }
        }
        // qubit 6: cross-wave butterfly via LDS exchange
        {
            const float c = cs[6], s = sn[6];
            const float t = w ? s : -s;
            __syncthreads();
            #pragma unroll
            for (int r = 0; r < 32; ++r) exw[r] = v[r];
            __syncthreads();
            #pragma unroll
            for (int r = 0; r < 32; ++r) v[r] = c * v[r] + t * exp_[r];
        }
        // qubits 7-11: register butterflies
        #pragma unroll
        for (int b = 0; b < 5; ++b) {
            const float c = cs[7 + b], s = sn[7 + b];
            const int M = 1 << b;
            #pragma unroll
            for (int r = 0; r < 32; ++r) {
                if (!(r & M)) {
                    const float a0 = v[r], a1 = v[r | M];
                    v[r]     = c * a0 - s * a1;
                    v[r | M] = s * a0 + c * a1;
                }
            }
        }
        // CZ ring sign
        #pragma unroll
        for (int r = 0; r < 32; ++r) {
            const int P4 = __popc(r & (r >> 1) & 0xF) & 1;
            const int r0 = r & 1, r4 = (r >> 4) & 1;
            float f = r4 ? fB : fA;
            if (P4) f = -f;
            if (r0) f *= fw;
            v[r] *= f;
        }
    }

    unsigned short* outh = pe + (size_t)smp * K_EXT + w*64 + lane;
    unsigned short* outl = outh + DIM;
    #pragma unroll
    for (int r = 0; r < 32; ++r) {
        const float x = v[r];
        const unsigned short hb = f32_to_bf16(x);
        outh[r*128] = hb;
        outl[r*128] = f32_to_bf16(x - bf16_to_f32(hb));
    }
}

// ---------------------------------------------------------------------------
// Kernel 2a: partial Gram.  1088 blocks = 136 tiles x 8 K-slices.
// TILE-MAJOR decode (tile = bid>>3, slice = bid&7): under round-robin XCD
// assignment each XCD owns ONE K-slice (2048 rows x 1024 k x 2 B = 4.0 MiB
// = its whole L2), walked bi-major — converts the 557 MB logical L2-fill
// stream (R14's saturated resource) into L2 hits.  Numerically identical.
// All registers NAMED (indexed register arrays spill on this compiler).
// ---------------------------------------------------------------------------
__global__ __launch_bounds__(256, 2) void gram_partial(const unsigned short* __restrict__ pe,
                                                       float* __restrict__ Gp)
{
    __shared__ __align__(16) unsigned short As[128*LDK];   // 18.4 KiB
    __shared__ __align__(16) unsigned short Bs[128*LDK];   // 18.4 KiB

    const int tid   = threadIdx.x;
    const int tile  = blockIdx.x >> 3;     // bi-major tile walk per XCD
    const int slice = blockIdx.x & 7;      // one K-slice per XCD (bid % 8)
    int bi, bj; tri_decode(tile, bi, bj);
    const int k0 = slice * KSL;

    const int wave = tid >> 6, lane = tid & 63;
    const int qr = (wave >> 1) * 64;   // quadrant row offset
    const int qc = (wave &  1) * 64;   // quadrant col offset
    const int mrow = lane & 31;
    const int kgrp = (lane >> 5) * 8;  // A/B layout: lane holds M[lane&31][(lane>>5)*8+j]

    floatx16 c00, c01, c10, c11;
    #pragma unroll
    for (int i = 0; i < 16; ++i) { c00[i]=0.f; c01[i]=0.f; c10[i]=0.f; c11[i]=0.f; }

    const int r = tid >> 1;
    const int h = (tid & 1) * 32;      // ushort offset (64 B)
    const unsigned short* gA = pe + ((size_t)bi*128 + r) * K_EXT + k0 + h;
    const unsigned short* gB = pe + ((size_t)bj*128 + r) * K_EXT + k0 + h;
    unsigned short* sA = &As[r*LDK + h];
    unsigned short* sB = &Bs[r*LDK + h];

    uint4 pa0 = *(const uint4*)(gA +  0), pa1 = *(const uint4*)(gA +  8);
    uint4 pa2 = *(const uint4*)(gA + 16), pa3 = *(const uint4*)(gA + 24);
    uint4 pb0 = *(const uint4*)(gB +  0), pb1 = *(const uint4*)(gB +  8);
    uint4 pb2 = *(const uint4*)(gB + 16), pb3 = *(const uint4*)(gB + 24);

    for (int kk = 0; kk < KSL; kk += BK) {
        __syncthreads();                       // prev readers done
        *(uint4*)(sA +  0) = pa0; *(uint4*)(sA +  8) = pa1;
        *(uint4*)(sA + 16) = pa2; *(uint4*)(sA + 24) = pa3;
        *(uint4*)(sB +  0) = pb0; *(uint4*)(sB +  8) = pb1;
        *(uint4*)(sB + 16) = pb2; *(uint4*)(sB + 24) = pb3;
        __syncthreads();
        if (kk + BK < KSL) {                   // prefetch next stage
            pa0 = *(const uint4*)(gA + kk + BK +  0); pa1 = *(const uint4*)(gA + kk + BK +  8);
            pa2 = *(const uint4*)(gA + kk + BK + 16); pa3 = *(const uint4*)(gA + kk + BK + 24);
            pb0 = *(const uint4*)(gB + kk + BK +  0); pb1 = *(const uint4*)(gB + kk + BK +  8);
            pb2 = *(const uint4*)(gB + kk + BK + 16); pb3 = *(const uint4*)(gB + kk + BK + 24);
        }
        #pragma unroll
        for (int ks = 0; ks < 4; ++ks) {
            const int ro = ks*16 + kgrp;
            const bf16x8 a0 = *(const bf16x8*)&As[(qr +      mrow)*LDK + ro];
            const bf16x8 a1 = *(const bf16x8*)&As[(qr + 32 + mrow)*LDK + ro];
            const bf16x8 b0 = *(const bf16x8*)&Bs[(qc +      mrow)*LDK + ro];
            const bf16x8 b1 = *(const bf16x8*)&Bs[(qc + 32 + mrow)*LDK + ro];
            c00 = __builtin_amdgcn_mfma_f32_32x32x16_bf16(a0, b0, c00, 0, 0, 0);
            c01 = __builtin_amdgcn_mfma_f32_32x32x16_bf16(a0, b1, c01, 0, 0, 0);
            c10 = __builtin_amdgcn_mfma_f32_32x32x16_bf16(a1, b0, c10, 0, 0, 0);
            c11 = __builtin_amdgcn_mfma_f32_32x32x16_bf16(a1, b1, c11, 0, 0, 0);
        }
    }

    // Write partial G quadrants.  C/D layout (m74/m101).
    float* Gt = Gp + ((size_t)slice * NTRI2 + tile) * 16384;
    const int crow = (lane >> 5) * 4;
    const int ccol = lane & 31;
    #pragma unroll
    for (int rr = 0; rr < 16; ++rr) {
        const int rl = (rr & 3) + 8*(rr >> 2) + crow;    // 0..31
        const int r0 = qr + rl,  r1 = qr + 32 + rl;
        const int cA = qc + ccol, cB = qc + 32 + ccol;
        Gt[r0*128 + cA] = c00[rr];
        Gt[r0*128 + cB] = c01[rr];
        Gt[r1*128 + cA] = c10[rr];
        Gt[r1*128 + cB] = c11[rr];
    }
}

// ---------------------------------------------------------------------------
// Kernel 2b: sum the 8 K-slice partials, square, weight, reduce.
// 544 blocks, each a quarter-tile (4096 elements), 8 strided reads/elem.
// ---------------------------------------------------------------------------
__global__ __launch_bounds__(256) void gram_reduce(const float* __restrict__ Gp,
                                                   const int* __restrict__ labels,
                                                   double* __restrict__ part1,
                                                   double* __restrict__ part2)
{
    __shared__ float la[128], lb[128];
    __shared__ double red[256];
    const int tid  = threadIdx.x;
    const int tile = blockIdx.x >> 2;
    const int quar = blockIdx.x & 3;
    int bi, bj; tri_decode(tile, bi, bj);

    if (tid < 128) la[tid]       = 2.0f*(float)labels[bi*128 + tid]       - 1.0f;
    else           lb[tid - 128] = 2.0f*(float)labels[bj*128 + tid - 128] - 1.0f;
    __syncthreads();

    const size_t stride = (size_t)NTRI2 * 16384;
    const float* g0 = Gp + (size_t)tile * 16384 + quar * 4096;

    double s1 = 0.0, s2 = 0.0;
    #pragma unroll 2
    for (int u = 0; u < 16; ++u) {
        const int e  = u*256 + tid;          // 0..4095 within quarter
        const int ge = quar*4096 + e;
        float g = 0.f;
        #pragma unroll
        for (int s = 0; s < NSLICE; ++s) g += g0[e + (size_t)s*stride];
        const int row = ge >> 7, col = ge & 127;
        const float w = (bi < bj) ? 2.0f : ((row < col) ? 2.0f : ((row == col) ? 1.0f : 0.0f));
        const float g2 = g * g;
        s1 += (double)(w * la[row] * lb[col] * g2);
        const double d = (double)g2;
        s2 += (double)w * d * d;
    }

    red[tid] = s1; __syncthreads();
    for (int off = 128; off; off >>= 1) { if (tid < off) red[tid] += red[tid+off]; __syncthreads(); }
    if (tid == 0) part1[blockIdx.x] = red[0];
    __syncthreads();
    red[tid] = s2; __syncthreads();
    for (int off = 128; off; off >>= 1) { if (tid < off) red[tid] += red[tid+off]; __syncthreads(); }
    if (tid == 0) part2[blockIdx.x] = red[0];
}

// ---------------------------------------------------------------------------
// Kernel 3: reduce 544 partial slots -> scalar f32.
// square_sum_l = N^2 exactly, so out = s1 / (N * sqrt(s2)).
// ---------------------------------------------------------------------------
__global__ __launch_bounds__(256) void finalize_kernel(const double* __restrict__ part1,
                                                       const double* __restrict__ part2,
                                                       float* __restrict__ out)
{
    __shared__ double r1[256], r2[256];
    const int tid = threadIdx.x;
    double a = 0.0, b = 0.0;
    #pragma unroll
    for (int u = 0; u < 3; ++u) {
        const int s = tid + u*256;
        if (s < NTRI2*4) { a += part1[s]; b += part2[s]; }
    }
    r1[tid] = a; r2[tid] = b; __syncthreads();
    for (int off = 128; off; off >>= 1) {
        if (tid < off) { r1[tid] += r1[tid+off]; r2[tid] += r2[tid+off]; }
        __syncthreads();
    }
    if (tid == 0) out[0] = (float)(r1[0] / (sqrt(r2[0]) * (double)NSAMP));
}

// ---------------------------------------------------------------------------
extern "C" void kernel_launch(void* const* d_in, const int* in_sizes, int n_in,
                              void* d_out, int out_size, void* d_ws, size_t ws_size,
                              hipStream_t stream)
{
    const float* data   = (const float*)d_in[0]; // (2048,12) f32
    const int*   labels = (const int*)d_in[1];   // (2048,)   i32
    const float* params = (const float*)d_in[2]; // (3,12)    f32

    double* part1 = (double*)d_ws;                                    // 544 (pad 768) doubles
    double* part2 = part1 + 768;                                      // 544 doubles
    unsigned short* psi_ext = (unsigned short*)((char*)d_ws + 16384); // 32 MiB
    float* Gp = (float*)((char*)d_ws + 16384 + (size_t)NSAMP*K_EXT*2);// 8x136x16384 f32 = 71.3 MiB

    sim_kernel<<<NSAMP/2, 256, 0, stream>>>(data, params, psi_ext);
    gram_partial<<<NTRI2*NSLICE, 256, 0, stream>>>(psi_ext, Gp);
    gram_reduce<<<NTRI2*4, 256, 0, stream>>>(Gp, labels, part1, part2);
    finalize_kernel<<<1, 256, 0, stream>>>(part1, part2, (float*)d_out);
}